// Round 3
// baseline (1891.116 us; speedup 1.0000x reference)
//
#include <hip/hip_runtime.h>
#include <cstdint>
#include <cstddef>

// ---------------------------------------------------------------------------
// GNS model: restructured dataflow (R2) + split-bf16 MFMA GEMM cores (R3).
//   Every 128x128 GEMM runs on the matrix pipe as 3 bf16 MFMAs per product
//   (AhBh + AlBh + AhBl), fp32 accumulate: rel err ~2^-17.
//   Weights are transposed+split once per call into WT ([n][k] bf16 hi/lo).
//   h lives only as bf16 hi/lo planes (hSh/hSl) -> node GEMMs read A-frags
//   directly from global (no LDS). Edge kernel stages recomputed U in LDS
//   (36.9 KB -> 4 blocks/CU) and reuses R2's run-accumulate atomic scatter.
// ---------------------------------------------------------------------------

#define DEVI static __device__ __forceinline__

typedef __bf16 bf16_t;
typedef bf16_t bf16x8 __attribute__((ext_vector_type(8)));
typedef bf16_t bf16x4 __attribute__((ext_vector_type(4)));
typedef float f32x4v __attribute__((ext_vector_type(4)));

DEVI float4 ld4(const float* p) { return *(const float4*)p; }
DEVI void st4(float* p, float4 v) { *(float4*)p = v; }
DEVI float prelu1(float z, float a) { return z > 0.f ? z : a * z; }
DEVI void atomicAddF(float* p, float v) {
  __hip_atomic_fetch_add(p, v, __ATOMIC_RELAXED, __HIP_MEMORY_SCOPE_AGENT);
}
DEVI f32x4v mfma_bf16(bf16x8 a, bf16x8 b, f32x4v c) {
  return __builtin_amdgcn_mfma_f32_16x16x32_bf16(a, b, c, 0, 0, 0);
}
// acc += A*B with A,B split hi/lo (drop lo*lo term, ~2^-18 rel)
DEVI void mfma3(f32x4v& acc, bf16x8 ah, bf16x8 al, bf16x8 bh, bf16x8 bl) {
  acc = mfma_bf16(ah, bh, acc);
  acc = mfma_bf16(al, bh, acc);
  acc = mfma_bf16(ah, bl, acc);
}
DEVI void split2(float x, bf16_t& h, bf16_t& l) {
  h = (bf16_t)x;
  l = (bf16_t)(x - (float)h);
}
DEVI bf16x8 ldb8(const bf16_t* p) { return *(const bf16x8*)p; }

// MFMA geometry (16x16x32): block=256thr=4 waves; wave handles rows
// [wave*32, wave*32+32) as 2 m-tiles x 8 n-tiles (full 128 cols).
// A-frag: lane supplies A[m = tile+ (l&15)][k = kstep*32 + (l>>4)*8 + j]
// B-frag: lane supplies B[k][n = tile + (l&15)] -> read from Bt[n][k] bf16.
// C/D:    lane holds D[row = tile + (l>>4)*4 + reg][col = tile + (l&15)].

#define SKP 72   // LDS A row stride in bf16 elems (64-chunk + 8 pad; 144 B, 16B-aligned, 2-way banks)

// ---------------------------------------------------------------------------
// k_pq: P = h@W1a, Q = h@W1b. A-frags from global hS planes, no LDS.
// ---------------------------------------------------------------------------
__global__ __launch_bounds__(256, 4) void k_pq(
    const bf16_t* __restrict__ hSh, const bf16_t* __restrict__ hSl,
    const bf16_t* __restrict__ W1T,   // [2 mats][hi|lo][128][128]
    float* __restrict__ P, float* __restrict__ Q, int M)
{
  const int t = threadIdx.x, lane = t & 63, wave = t >> 6;
  const int p = lane & 15, q = lane >> 4;
  const int row0 = blockIdx.x * 128;
  const bf16_t* Bh = W1T + (size_t)blockIdx.y * 32768;
  const bf16_t* Bl = Bh + 16384;
  float* O = blockIdx.y ? Q : P;

  f32x4v acc[2][8];
  #pragma unroll
  for (int i = 0; i < 2; ++i)
    #pragma unroll
    for (int j = 0; j < 8; ++j) acc[i][j] = (f32x4v){0.f, 0.f, 0.f, 0.f};

  const size_t ra0 = (size_t)(row0 + wave * 32 + p) * 128;
  const size_t ra1 = ra0 + 16 * 128;

  #pragma unroll
  for (int ks = 0; ks < 4; ++ks) {
    const int k0 = ks * 32 + q * 8;
    bf16x8 aH0 = ldb8(hSh + ra0 + k0), aH1 = ldb8(hSh + ra1 + k0);
    bf16x8 aL0 = ldb8(hSl + ra0 + k0), aL1 = ldb8(hSl + ra1 + k0);
    #pragma unroll
    for (int nt = 0; nt < 8; ++nt) {
      const bf16_t* bp = Bh + (size_t)(nt * 16 + p) * 128 + k0;
      bf16x8 bH = ldb8(bp);
      bf16x8 bL = ldb8(bp + 16384);
      mfma3(acc[0][nt], aH0, aL0, bH, bL);
      mfma3(acc[1][nt], aH1, aL1, bH, bL);
    }
  }
  #pragma unroll
  for (int mt = 0; mt < 2; ++mt)
    #pragma unroll
    for (int nt = 0; nt < 8; ++nt) {
      int rb = row0 + wave * 32 + mt * 16 + q * 4;
      int col = nt * 16 + p;
      #pragma unroll
      for (int r = 0; r < 4; ++r)
        if (rb + r < M) O[(size_t)(rb + r) * 128 + col] = acc[mt][nt][r];
    }
}

// ---------------------------------------------------------------------------
// k_edge: U recomputed+split -> LDS; MFMA vs WhatT; C reshaped via LDS;
// epilogue + P[dst]+Q[src]+bvec, prelu, run-accumulate atomic scatter.
// ---------------------------------------------------------------------------
__global__ __launch_bounds__(256, 4) void k_edge(
    const float* __restrict__ sEa, const int* __restrict__ sSrc,
    const int* __restrict__ sDst,
    const float* __restrict__ ee_w1, const float* __restrict__ ee_b1,
    const float* __restrict__ ee_a,
    const bf16_t* __restrict__ WhatT, const float* __restrict__ bvec,
    const float* __restrict__ alpha_ptr,
    const float* __restrict__ P, const float* __restrict__ Q,
    float* __restrict__ S, int E)
{
  __shared__ float smem[9216];                 // 36864 B
  bf16_t* Ah = (bf16_t*)smem;                  // [128][SKP]
  bf16_t* Al = Ah + 128 * SKP;
  float (*Cs)[68] = (float(*)[68])smem;        // overlays A after k-loop

  const int t = threadIdx.x, lane = t & 63, wave = t >> 6;
  const int p = lane & 15, q = lane >> 4;
  const int e0 = blockIdx.x * 128;
  const float ua = *ee_a;
  const bf16_t* Bh = WhatT;
  const bf16_t* Bl = WhatT + 16384;

  f32x4v acc[2][8];
  #pragma unroll
  for (int i = 0; i < 2; ++i)
    #pragma unroll
    for (int j = 0; j < 8; ++j) acc[i][j] = (f32x4v){0.f, 0.f, 0.f, 0.f};

  for (int c = 0; c < 2; ++c) {
    // --- stage U chunk (cols c*64..c*64+63), split to bf16 hi/lo ---
    {
      const int kc2 = (t & 15) << 2;          // 0..60 within chunk
      const int kg = c * 64 + kc2;
      float4 w0 = ld4(ee_w1 + 0 * 128 + kg);
      float4 w1 = ld4(ee_w1 + 1 * 128 + kg);
      float4 w2 = ld4(ee_w1 + 2 * 128 + kg);
      float4 w3 = ld4(ee_w1 + 3 * 128 + kg);
      float4 bb = ld4(ee_b1 + kg);
      #pragma unroll
      for (int i = 0; i < 8; ++i) {
        int m = (t >> 4) * 8 + i;
        int ed = e0 + m;
        float4 eav = make_float4(0.f, 0.f, 0.f, 0.f);
        if (ed < E) eav = ld4(sEa + (size_t)ed * 4);
        float ux = bb.x, uy = bb.y, uz = bb.z, uw = bb.w;
        ux = fmaf(eav.x, w0.x, ux); uy = fmaf(eav.x, w0.y, uy);
        uz = fmaf(eav.x, w0.z, uz); uw = fmaf(eav.x, w0.w, uw);
        ux = fmaf(eav.y, w1.x, ux); uy = fmaf(eav.y, w1.y, uy);
        uz = fmaf(eav.y, w1.z, uz); uw = fmaf(eav.y, w1.w, uw);
        ux = fmaf(eav.z, w2.x, ux); uy = fmaf(eav.z, w2.y, uy);
        uz = fmaf(eav.z, w2.z, uz); uw = fmaf(eav.z, w2.w, uw);
        ux = fmaf(eav.w, w3.x, ux); uy = fmaf(eav.w, w3.y, uy);
        uz = fmaf(eav.w, w3.z, uz); uw = fmaf(eav.w, w3.w, uw);
        ux = prelu1(ux, ua); uy = prelu1(uy, ua);
        uz = prelu1(uz, ua); uw = prelu1(uw, ua);
        bf16_t h0, l0, h1, l1, h2, l2, h3, l3;
        split2(ux, h0, l0); split2(uy, h1, l1);
        split2(uz, h2, l2); split2(uw, h3, l3);
        *(bf16x4*)(Ah + m * SKP + kc2) = (bf16x4){h0, h1, h2, h3};
        *(bf16x4*)(Al + m * SKP + kc2) = (bf16x4){l0, l1, l2, l3};
      }
    }
    __syncthreads();
    #pragma unroll
    for (int ks = 0; ks < 2; ++ks) {
      const int klds = ks * 32 + q * 8;
      const int kglob = c * 64 + klds;
      bf16x8 aH0 = ldb8(Ah + (wave * 32 + p) * SKP + klds);
      bf16x8 aH1 = ldb8(Ah + (wave * 32 + 16 + p) * SKP + klds);
      bf16x8 aL0 = ldb8(Al + (wave * 32 + p) * SKP + klds);
      bf16x8 aL1 = ldb8(Al + (wave * 32 + 16 + p) * SKP + klds);
      #pragma unroll
      for (int nt = 0; nt < 8; ++nt) {
        const bf16_t* bp = Bh + (size_t)(nt * 16 + p) * 128 + kglob;
        bf16x8 bH = ldb8(bp);
        bf16x8 bL = ldb8(bp + 16384);
        mfma3(acc[0][nt], aH0, aL0, bH, bL);
        mfma3(acc[1][nt], aH1, aL1, bH, bL);
      }
    }
    __syncthreads();
  }

  // --- epilogue: reshape C via LDS in 2 col-halves, run-accumulate scatter ---
  const float alpha = *alpha_ptr;
  const int r0 = (t >> 4) * 8;
  const int c0 = (t & 15) * 4;
  for (int nh = 0; nh < 2; ++nh) {
    #pragma unroll
    for (int mt = 0; mt < 2; ++mt)
      #pragma unroll
      for (int j = 0; j < 4; ++j) {
        f32x4v v = acc[mt][nh * 4 + j];
        int col = j * 16 + p;
        int row = wave * 32 + mt * 16 + q * 4;
        Cs[row + 0][col] = v[0]; Cs[row + 1][col] = v[1];
        Cs[row + 2][col] = v[2]; Cs[row + 3][col] = v[3];
      }
    __syncthreads();
    const int gc = nh * 64 + c0;
    const float4 bv = ld4(bvec + gc);
    int curd = -1;
    float4 sa = make_float4(0.f, 0.f, 0.f, 0.f);
    #pragma unroll
    for (int i = 0; i < 8; ++i) {
      int ed = e0 + r0 + i;
      int d = (ed < E) ? sDst[ed] : -2;
      if (d >= 0) {
        int sr = sSrc[ed];
        float4 cv = *(const float4*)(&Cs[r0 + i][c0]);
        float4 pv = ld4(P + (size_t)d * 128 + gc);
        float4 qv = ld4(Q + (size_t)sr * 128 + gc);
        float4 za;
        za.x = prelu1(cv.x + pv.x + qv.x + bv.x, alpha);
        za.y = prelu1(cv.y + pv.y + qv.y + bv.y, alpha);
        za.z = prelu1(cv.z + pv.z + qv.z + bv.z, alpha);
        za.w = prelu1(cv.w + pv.w + qv.w + bv.w, alpha);
        if (d == curd) {
          sa.x += za.x; sa.y += za.y; sa.z += za.z; sa.w += za.w;
        } else {
          if (curd >= 0) {
            float* pp = S + (size_t)curd * 128 + gc;
            atomicAddF(pp + 0, sa.x); atomicAddF(pp + 1, sa.y);
            atomicAddF(pp + 2, sa.z); atomicAddF(pp + 3, sa.w);
          }
          curd = d; sa = za;
        }
      } else if (curd >= 0) {
        float* pp = S + (size_t)curd * 128 + gc;
        atomicAddF(pp + 0, sa.x); atomicAddF(pp + 1, sa.y);
        atomicAddF(pp + 2, sa.z); atomicAddF(pp + 3, sa.w);
        curd = -1;
      }
    }
    if (curd >= 0) {
      float* pp = S + (size_t)curd * 128 + gc;
      atomicAddF(pp + 0, sa.x); atomicAddF(pp + 1, sa.y);
      atomicAddF(pp + 2, sa.z); atomicAddF(pp + 3, sa.w);
    }
    __syncthreads();
  }
}

// ---------------------------------------------------------------------------
// k_svu: acc1 = S@Wtil (LDS-staged split) + h@Wn1a (global frags);
//        V = prelu(acc1 + ln_b1 + deg*btil); h += V@ln_w2 + ln_b2 (V via LDS);
//        writes updated hS splits.
// ---------------------------------------------------------------------------
__global__ __launch_bounds__(256, 2) void k_svu(
    const float* __restrict__ Sbuf,
    bf16_t* __restrict__ hSh, bf16_t* __restrict__ hSl,
    const bf16_t* __restrict__ WtilT, const bf16_t* __restrict__ Wn1aT,
    const bf16_t* __restrict__ lnw2T,
    const float* __restrict__ ln_b1_l, const float* __restrict__ btil_l,
    const int* __restrict__ deg, const float* __restrict__ ln_a_l,
    const float* __restrict__ ln_b2_l, int M)
{
  __shared__ float smem[9216];
  bf16_t* Ah = (bf16_t*)smem;
  bf16_t* Al = Ah + 128 * SKP;

  const int t = threadIdx.x, lane = t & 63, wave = t >> 6;
  const int p = lane & 15, q = lane >> 4;
  const int row0 = blockIdx.x * 128;

  f32x4v acc1[2][8];
  #pragma unroll
  for (int i = 0; i < 2; ++i)
    #pragma unroll
    for (int j = 0; j < 8; ++j) acc1[i][j] = (f32x4v){0.f, 0.f, 0.f, 0.f};

  // GEMM 1a: S@Wtil, LDS-staged with split
  for (int c = 0; c < 2; ++c) {
    #pragma unroll
    for (int it = 0; it < 8; ++it) {
      int idx = it * 256 + t;
      int row = idx >> 4, kc = (idx & 15) << 2;
      float4 v = ld4(Sbuf + (size_t)(row0 + row) * 128 + c * 64 + kc);
      bf16_t h0, l0, h1, l1, h2, l2, h3, l3;
      split2(v.x, h0, l0); split2(v.y, h1, l1);
      split2(v.z, h2, l2); split2(v.w, h3, l3);
      *(bf16x4*)(Ah + row * SKP + kc) = (bf16x4){h0, h1, h2, h3};
      *(bf16x4*)(Al + row * SKP + kc) = (bf16x4){l0, l1, l2, l3};
    }
    __syncthreads();
    #pragma unroll
    for (int ks = 0; ks < 2; ++ks) {
      const int klds = ks * 32 + q * 8;
      const int kglob = c * 64 + klds;
      bf16x8 aH0 = ldb8(Ah + (wave * 32 + p) * SKP + klds);
      bf16x8 aH1 = ldb8(Ah + (wave * 32 + 16 + p) * SKP + klds);
      bf16x8 aL0 = ldb8(Al + (wave * 32 + p) * SKP + klds);
      bf16x8 aL1 = ldb8(Al + (wave * 32 + 16 + p) * SKP + klds);
      #pragma unroll
      for (int nt = 0; nt < 8; ++nt) {
        const bf16_t* bp = WtilT + (size_t)(nt * 16 + p) * 128 + kglob;
        bf16x8 bH = ldb8(bp);
        bf16x8 bL = ldb8(bp + 16384);
        mfma3(acc1[0][nt], aH0, aL0, bH, bL);
        mfma3(acc1[1][nt], aH1, aL1, bH, bL);
      }
    }
    __syncthreads();
  }
  // GEMM 1b: h@Wn1a, global frags
  {
    const size_t ra0 = (size_t)(row0 + wave * 32 + p) * 128;
    const size_t ra1 = ra0 + 16 * 128;
    #pragma unroll
    for (int ks = 0; ks < 4; ++ks) {
      const int k0 = ks * 32 + q * 8;
      bf16x8 aH0 = ldb8(hSh + ra0 + k0), aH1 = ldb8(hSh + ra1 + k0);
      bf16x8 aL0 = ldb8(hSl + ra0 + k0), aL1 = ldb8(hSl + ra1 + k0);
      #pragma unroll
      for (int nt = 0; nt < 8; ++nt) {
        const bf16_t* bp = Wn1aT + (size_t)(nt * 16 + p) * 128 + k0;
        bf16x8 bH = ldb8(bp);
        bf16x8 bL = ldb8(bp + 16384);
        mfma3(acc1[0][nt], aH0, aL0, bH, bL);
        mfma3(acc1[1][nt], aH1, aL1, bH, bL);
      }
    }
  }
  // V = prelu(acc1 + ln_b1 + deg*btil)  (in place, C layout)
  const float alpha = *ln_a_l;
  float degf[2][4];
  #pragma unroll
  for (int mt = 0; mt < 2; ++mt)
    #pragma unroll
    for (int r = 0; r < 4; ++r) {
      int row = row0 + wave * 32 + mt * 16 + q * 4 + r;
      degf[mt][r] = (row < M) ? (float)deg[row] : 0.f;
    }
  #pragma unroll
  for (int nt = 0; nt < 8; ++nt) {
    int col = nt * 16 + p;
    float b1 = ln_b1_l[col], bt = btil_l[col];
    #pragma unroll
    for (int mt = 0; mt < 2; ++mt)
      #pragma unroll
      for (int r = 0; r < 4; ++r)
        acc1[mt][nt][r] = prelu1(acc1[mt][nt][r] + b1 + degf[mt][r] * bt, alpha);
  }

  // GEMM 2: acc2 = V@ln_w2 (V -> LDS split per chunk)
  f32x4v acc2[2][8];
  #pragma unroll
  for (int i = 0; i < 2; ++i)
    #pragma unroll
    for (int j = 0; j < 8; ++j) acc2[i][j] = (f32x4v){0.f, 0.f, 0.f, 0.f};
  for (int c = 0; c < 2; ++c) {
    __syncthreads();
    #pragma unroll
    for (int mt = 0; mt < 2; ++mt)
      #pragma unroll
      for (int j = 0; j < 4; ++j) {
        int kk = j * 16 + p;
        #pragma unroll
        for (int r = 0; r < 4; ++r) {
          int row = wave * 32 + mt * 16 + q * 4 + r;
          bf16_t hb, lb;
          split2(acc1[mt][c * 4 + j][r], hb, lb);
          Ah[row * SKP + kk] = hb;
          Al[row * SKP + kk] = lb;
        }
      }
    __syncthreads();
    #pragma unroll
    for (int ks = 0; ks < 2; ++ks) {
      const int klds = ks * 32 + q * 8;
      const int kglob = c * 64 + klds;
      bf16x8 aH0 = ldb8(Ah + (wave * 32 + p) * SKP + klds);
      bf16x8 aH1 = ldb8(Ah + (wave * 32 + 16 + p) * SKP + klds);
      bf16x8 aL0 = ldb8(Al + (wave * 32 + p) * SKP + klds);
      bf16x8 aL1 = ldb8(Al + (wave * 32 + 16 + p) * SKP + klds);
      #pragma unroll
      for (int nt = 0; nt < 8; ++nt) {
        const bf16_t* bp = lnw2T + (size_t)(nt * 16 + p) * 128 + kglob;
        bf16x8 bH = ldb8(bp);
        bf16x8 bL = ldb8(bp + 16384);
        mfma3(acc2[0][nt], aH0, aL0, bH, bL);
        mfma3(acc2[1][nt], aH1, aL1, bH, bL);
      }
    }
  }
  // h += acc2 + ln_b2 ; rewrite splits
  #pragma unroll
  for (int mt = 0; mt < 2; ++mt)
    #pragma unroll
    for (int nt = 0; nt < 8; ++nt) {
      int col = nt * 16 + p;
      float b2 = ln_b2_l[col];
      int rb = row0 + wave * 32 + mt * 16 + q * 4;
      #pragma unroll
      for (int r = 0; r < 4; ++r) {
        int row = rb + r;
        if (row < M) {
          size_t idx = (size_t)row * 128 + col;
          float hv = (float)hSh[idx] + (float)hSl[idx] + acc2[mt][nt][r] + b2;
          bf16_t hb, lb;
          split2(hv, hb, lb);
          hSh[idx] = hb; hSl[idx] = lb;
        }
      }
    }
}

// ---------------------------------------------------------------------------
// k_enc: h = UN@ne_w2 + ne_b2 -> write hS splits. UN f32, LDS-staged split.
// ---------------------------------------------------------------------------
__global__ __launch_bounds__(256, 4) void k_enc(
    const float* __restrict__ UN, const bf16_t* __restrict__ BT,
    const float* __restrict__ b2,
    bf16_t* __restrict__ hSh, bf16_t* __restrict__ hSl, int M)
{
  __shared__ float smem[9216];
  bf16_t* Ah = (bf16_t*)smem;
  bf16_t* Al = Ah + 128 * SKP;
  const int t = threadIdx.x, lane = t & 63, wave = t >> 6;
  const int p = lane & 15, q = lane >> 4;
  const int row0 = blockIdx.x * 128;

  f32x4v acc[2][8];
  #pragma unroll
  for (int i = 0; i < 2; ++i)
    #pragma unroll
    for (int j = 0; j < 8; ++j) acc[i][j] = (f32x4v){0.f, 0.f, 0.f, 0.f};

  for (int c = 0; c < 2; ++c) {
    #pragma unroll
    for (int it = 0; it < 8; ++it) {
      int idx = it * 256 + t;
      int row = idx >> 4, kc = (idx & 15) << 2;
      float4 v = make_float4(0.f, 0.f, 0.f, 0.f);
      if (row0 + row < M) v = ld4(UN + (size_t)(row0 + row) * 128 + c * 64 + kc);
      bf16_t h0, l0, h1, l1, h2, l2, h3, l3;
      split2(v.x, h0, l0); split2(v.y, h1, l1);
      split2(v.z, h2, l2); split2(v.w, h3, l3);
      *(bf16x4*)(Ah + row * SKP + kc) = (bf16x4){h0, h1, h2, h3};
      *(bf16x4*)(Al + row * SKP + kc) = (bf16x4){l0, l1, l2, l3};
    }
    __syncthreads();
    #pragma unroll
    for (int ks = 0; ks < 2; ++ks) {
      const int klds = ks * 32 + q * 8;
      const int kglob = c * 64 + klds;
      bf16x8 aH0 = ldb8(Ah + (wave * 32 + p) * SKP + klds);
      bf16x8 aH1 = ldb8(Ah + (wave * 32 + 16 + p) * SKP + klds);
      bf16x8 aL0 = ldb8(Al + (wave * 32 + p) * SKP + klds);
      bf16x8 aL1 = ldb8(Al + (wave * 32 + 16 + p) * SKP + klds);
      #pragma unroll
      for (int nt = 0; nt < 8; ++nt) {
        const bf16_t* bp = BT + (size_t)(nt * 16 + p) * 128 + kglob;
        bf16x8 bH = ldb8(bp);
        bf16x8 bL = ldb8(bp + 16384);
        mfma3(acc[0][nt], aH0, aL0, bH, bL);
        mfma3(acc[1][nt], aH1, aL1, bH, bL);
      }
    }
    __syncthreads();
  }
  #pragma unroll
  for (int mt = 0; mt < 2; ++mt)
    #pragma unroll
    for (int nt = 0; nt < 8; ++nt) {
      int col = nt * 16 + p;
      float bc = b2[col];
      int rb = row0 + wave * 32 + mt * 16 + q * 4;
      #pragma unroll
      for (int r = 0; r < 4; ++r) {
        int row = rb + r;
        if (row < M) {
          size_t idx = (size_t)row * 128 + col;
          float hv = acc[mt][nt][r] + bc;
          bf16_t hb, lb;
          split2(hv, hb, lb);
          hSh[idx] = hb; hSl[idx] = lb;
        }
      }
    }
}

// ---------------------------------------------------------------------------
// k_dec: out = prelu(h@de_w1+de_b1, de_a)@de_w2 + de_b2. GEMM1 via global
// frags; V reshaped through LDS in halves for the 3-col contraction.
// ---------------------------------------------------------------------------
__global__ __launch_bounds__(256, 4) void k_dec(
    const bf16_t* __restrict__ hSh, const bf16_t* __restrict__ hSl,
    const bf16_t* __restrict__ dw1T,
    const float* __restrict__ de_b1, const float* __restrict__ de_a,
    const float* __restrict__ de_w2, const float* __restrict__ de_b2,
    float* __restrict__ out, int M)
{
  __shared__ float Cs[128][68];
  __shared__ float w2s[384];
  const int t = threadIdx.x, lane = t & 63, wave = t >> 6;
  const int p = lane & 15, q = lane >> 4;
  const int row0 = blockIdx.x * 128;
  for (int i = t; i < 384; i += 256) w2s[i] = de_w2[i];

  f32x4v acc[2][8];
  #pragma unroll
  for (int i = 0; i < 2; ++i)
    #pragma unroll
    for (int j = 0; j < 8; ++j) acc[i][j] = (f32x4v){0.f, 0.f, 0.f, 0.f};

  const size_t ra0 = (size_t)(row0 + wave * 32 + p) * 128;
  const size_t ra1 = ra0 + 16 * 128;
  #pragma unroll
  for (int ks = 0; ks < 4; ++ks) {
    const int k0 = ks * 32 + q * 8;
    bf16x8 aH0 = ldb8(hSh + ra0 + k0), aH1 = ldb8(hSh + ra1 + k0);
    bf16x8 aL0 = ldb8(hSl + ra0 + k0), aL1 = ldb8(hSl + ra1 + k0);
    #pragma unroll
    for (int nt = 0; nt < 8; ++nt) {
      const bf16_t* bp = dw1T + (size_t)(nt * 16 + p) * 128 + k0;
      bf16x8 bH = ldb8(bp);
      bf16x8 bL = ldb8(bp + 16384);
      mfma3(acc[0][nt], aH0, aL0, bH, bL);
      mfma3(acc[1][nt], aH1, aL1, bH, bL);
    }
  }
  const float alpha = *de_a;
  #pragma unroll
  for (int nt = 0; nt < 8; ++nt) {
    float bc = de_b1[nt * 16 + p];
    #pragma unroll
    for (int mt = 0; mt < 2; ++mt)
      #pragma unroll
      for (int r = 0; r < 4; ++r)
        acc[mt][nt][r] = prelu1(acc[mt][nt][r] + bc, alpha);
  }
  float s0 = de_b2[0], s1 = de_b2[1], s2 = de_b2[2];
  for (int nh = 0; nh < 2; ++nh) {
    #pragma unroll
    for (int mt = 0; mt < 2; ++mt)
      #pragma unroll
      for (int j = 0; j < 4; ++j) {
        f32x4v v = acc[mt][nh * 4 + j];
        int col = j * 16 + p;
        int row = wave * 32 + mt * 16 + q * 4;
        Cs[row + 0][col] = v[0]; Cs[row + 1][col] = v[1];
        Cs[row + 2][col] = v[2]; Cs[row + 3][col] = v[3];
      }
    __syncthreads();
    if (t < 128) {
      for (int k = 0; k < 64; ++k) {
        float vv = Cs[t][k];
        int gk = nh * 64 + k;
        s0 = fmaf(vv, w2s[gk * 3 + 0], s0);
        s1 = fmaf(vv, w2s[gk * 3 + 1], s1);
        s2 = fmaf(vv, w2s[gk * 3 + 2], s2);
      }
    }
    __syncthreads();
  }
  if (t < 128) {
    int row = row0 + t;
    if (row < M) {
      out[(size_t)row * 3 + 0] = s0;
      out[(size_t)row * 3 + 1] = s1;
      out[(size_t)row * 3 + 2] = s2;
    }
  }
}

// ---------------------------------------------------------------------------
// Weight prep: transpose+split plain weights; fold+transpose+split What/Wtil.
// WT slots (each 32768 bf16 = hi[128][128] then lo[128][128]):
//   0: ne_w2  1: de_w1  2+l*6+{0:W1a,1:W1b,2:Wn1a,3:ln_w2,4:What,5:Wtil}
// ---------------------------------------------------------------------------
__global__ __launch_bounds__(256) void k_tsplit(
    const float* __restrict__ ne_w2, const float* __restrict__ de_w1,
    const float* __restrict__ le_w1, const float* __restrict__ ln_w1,
    const float* __restrict__ ln_w2, bf16_t* __restrict__ WT)
{
  int jid = blockIdx.x;
  const float* src; int slot;
  if (jid == 0)      { src = ne_w2; slot = 0; }
  else if (jid == 1) { src = de_w1; slot = 1; }
  else {
    int l = (jid - 2) >> 2, wj = (jid - 2) & 3;
    slot = 2 + l * 6 + wj;
    src = (wj == 0) ? le_w1 + (size_t)l * 49152
        : (wj == 1) ? le_w1 + (size_t)l * 49152 + 16384
        : (wj == 2) ? ln_w1 + (size_t)l * 32768
                    : ln_w2 + (size_t)l * 16384;
  }
  bf16_t* oh = WT + (size_t)slot * 32768;
  bf16_t* ol = oh + 16384;
  for (int idx = threadIdx.x; idx < 16384; idx += 256) {
    int k = idx >> 7, n = idx & 127;
    float v = src[idx];
    bf16_t hb, lb;
    split2(v, hb, lb);
    oh[n * 128 + k] = hb;
    ol[n * 128 + k] = lb;
  }
}

__global__ __launch_bounds__(256) void k_fold(
    const float* __restrict__ ee_w2, const float* __restrict__ ee_b2,
    const float* __restrict__ le_w1, const float* __restrict__ le_b1,
    const float* __restrict__ le_w2, const float* __restrict__ le_b2,
    const float* __restrict__ ln_w1,
    bf16_t* __restrict__ WT, float* __restrict__ bvec, float* __restrict__ btil)
{
  const int l = blockIdx.x;
  const int which = blockIdx.y;
  const float* L; const float* Rm; const float* lb; const float* badd;
  int slot; float* bout;
  if (which == 0) {
    L = ee_w2; Rm = le_w1 + (size_t)l * 49152 + 256 * 128;
    lb = ee_b2; badd = le_b1 + l * 128;
    slot = 2 + l * 6 + 4; bout = bvec + l * 128;
  } else {
    L = le_w2 + (size_t)l * 16384; Rm = ln_w1 + (size_t)l * 32768 + 128 * 128;
    lb = le_b2 + l * 128; badd = nullptr;
    slot = 2 + l * 6 + 5; bout = btil + l * 128;
  }
  bf16_t* oh = WT + (size_t)slot * 32768;
  bf16_t* ol = oh + 16384;
  const int t = threadIdx.x;
  for (int eidx = t; eidx < 16384; eidx += 256) {
    int k = eidx >> 7, n = eidx & 127;
    float a = 0.f;
    for (int d = 0; d < 128; d += 4) {
      float4 lv = ld4(L + k * 128 + d);
      a = fmaf(lv.x, Rm[(d + 0) * 128 + n], a);
      a = fmaf(lv.y, Rm[(d + 1) * 128 + n], a);
      a = fmaf(lv.z, Rm[(d + 2) * 128 + n], a);
      a = fmaf(lv.w, Rm[(d + 3) * 128 + n], a);
    }
    bf16_t hb, lbv;
    split2(a, hb, lbv);
    oh[n * 128 + k] = hb;
    ol[n * 128 + k] = lbv;
  }
  if (t < 128) {
    float a = badd ? badd[t] : 0.f;
    for (int d = 0; d < 128; ++d) a = fmaf(lb[d], Rm[d * 128 + t], a);
    bout[t] = a;
  }
}

// First node-encoder layer: UN = prelu(x@ne_w1 + ne_b1)
__global__ __launch_bounds__(256) void k_node_u(
    const float* __restrict__ x, const float* __restrict__ w1,
    const float* __restrict__ b1, const float* __restrict__ a_ptr,
    float* __restrict__ U, int M)
{
  int gid = blockIdx.x * 256 + threadIdx.x;
  int m = gid >> 5;
  if (m >= M) return;
  int nc = (gid & 31) << 2;
  float a = *a_ptr;
  float4 bb = ld4(b1 + nc);
  float z0 = bb.x, z1 = bb.y, z2 = bb.z, z3 = bb.w;
  const float* xr = x + (size_t)m * 30;
  #pragma unroll
  for (int j = 0; j < 30; ++j) {
    float xv = xr[j];
    float4 wv = ld4(w1 + j * 128 + nc);
    z0 = fmaf(xv, wv.x, z0); z1 = fmaf(xv, wv.y, z1);
    z2 = fmaf(xv, wv.z, z2); z3 = fmaf(xv, wv.w, z3);
  }
  st4(U + (size_t)m * 128 + nc,
      make_float4(prelu1(z0, a), prelu1(z1, a), prelu1(z2, a), prelu1(z3, a)));
}

// --------- counting sort by dst ---------------------------------------------
__global__ void k_hist(const int* __restrict__ dstIdx, int* __restrict__ deg, int E) {
  int i = blockIdx.x * 256 + threadIdx.x;
  if (i < E) atomicAdd(deg + dstIdx[i], 1);
}

__global__ __launch_bounds__(1024) void k_scan(
    const int* __restrict__ deg, int* __restrict__ cursor, int N, int per)
{
  __shared__ int part[1024];
  const int t = threadIdx.x;
  const int base = t * per;
  int local = 0;
  for (int i = 0; i < per; ++i) {
    int idx = base + i;
    if (idx < N) local += deg[idx];
  }
  part[t] = local;
  __syncthreads();
  for (int off = 1; off < 1024; off <<= 1) {
    int v = (t >= off) ? part[t - off] : 0;
    __syncthreads();
    part[t] += v;
    __syncthreads();
  }
  int run = (t == 0) ? 0 : part[t - 1];
  for (int i = 0; i < per; ++i) {
    int idx = base + i;
    if (idx < N) { cursor[idx] = run; run += deg[idx]; }
  }
}

__global__ void k_scatter(const int* __restrict__ srcIdx, const int* __restrict__ dstIdx,
                          const float* __restrict__ ea, int* __restrict__ cursor,
                          int* __restrict__ sSrc, int* __restrict__ sDst,
                          float* __restrict__ sEa, int E)
{
  int e = blockIdx.x * 256 + threadIdx.x;
  if (e < E) {
    int d = dstIdx[e];
    int p = atomicAdd(cursor + d, 1);
    sSrc[p] = srcIdx[e];
    sDst[p] = d;
    st4(sEa + (size_t)p * 4, ld4(ea + (size_t)e * 4));
  }
}

// ---------------------------------------------------------------------------
extern "C" void kernel_launch(void* const* d_in, const int* in_sizes, int n_in,
                              void* d_out, int out_size, void* d_ws, size_t ws_size,
                              hipStream_t stream)
{
  const float* x     = (const float*)d_in[0];
  const float* ea    = (const float*)d_in[1];
  const int*   ei    = (const int*)  d_in[2];
  const float* ne_w1 = (const float*)d_in[3];
  const float* ne_b1 = (const float*)d_in[4];
  const float* ne_a  = (const float*)d_in[5];
  const float* ne_w2 = (const float*)d_in[6];
  const float* ne_b2 = (const float*)d_in[7];
  const float* ee_w1 = (const float*)d_in[8];
  const float* ee_b1 = (const float*)d_in[9];
  const float* ee_a  = (const float*)d_in[10];
  const float* ee_w2 = (const float*)d_in[11];
  const float* ee_b2 = (const float*)d_in[12];
  const float* le_w1 = (const float*)d_in[13];
  const float* le_b1 = (const float*)d_in[14];
  const float* le_a  = (const float*)d_in[15];
  const float* le_w2 = (const float*)d_in[16];
  const float* le_b2 = (const float*)d_in[17];
  const float* ln_w1 = (const float*)d_in[18];
  const float* ln_b1 = (const float*)d_in[19];
  const float* ln_a  = (const float*)d_in[20];
  const float* ln_w2 = (const float*)d_in[21];
  const float* ln_b2 = (const float*)d_in[22];
  const float* de_w1 = (const float*)d_in[23];
  const float* de_b1 = (const float*)d_in[24];
  const float* de_a  = (const float*)d_in[25];
  const float* de_w2 = (const float*)d_in[26];
  const float* de_b2 = (const float*)d_in[27];

  const int N = in_sizes[0] / 30;
  const int E = in_sizes[1] / 4;
  const int* srcIdx = ei;        // edge_index[0] = x_j (source)
  const int* dstIdx = ei + E;    // edge_index[1] = x_i (target / agg index)

  const int gN = (N + 127) / 128;
  const int gE = (E + 127) / 128;
  const int Np = gN * 128;
  const size_t NNp = (size_t)Np * 128;

  float* w = (float*)d_ws;
  float* Pb   = w; w += NNp;
  float* Qb   = w; w += NNp;
  float* Sb   = w; w += NNp;           // S; also UN before the layer loop
  float* bvec = w; w += 5 * 128;
  float* btil = w; w += 5 * 128;
  float* sEa  = w; w += (size_t)E * 4;
  bf16_t* hSh = (bf16_t*)w;
  bf16_t* hSl = hSh + NNp;  w += NNp;  // 2 bf16 planes == NNp floats
  bf16_t* WT  = (bf16_t*)w; w += 32 * 32768 / 2;
  int* ip     = (int*)w;
  int* deg    = ip; ip += N;
  int* cursor = ip; ip += N;
  int* sSrc   = ip; ip += E;
  int* sDst   = ip; ip += E;

  float* out = (float*)d_out;

  // weight prep
  k_tsplit<<<dim3(22), dim3(256), 0, stream>>>(ne_w2, de_w1, le_w1, ln_w1, ln_w2, WT);
  k_fold<<<dim3(5, 2), dim3(256), 0, stream>>>(ee_w2, ee_b2, le_w1, le_b1,
                                               le_w2, le_b2, ln_w1, WT, bvec, btil);
  // counting sort of edges by dst
  hipMemsetAsync(deg, 0, (size_t)N * 4, stream);
  k_hist<<<dim3((E + 255) / 256), dim3(256), 0, stream>>>(dstIdx, deg, E);
  k_scan<<<dim3(1), dim3(1024), 0, stream>>>(deg, cursor, N, (N + 1023) / 1024);
  k_scatter<<<dim3((E + 255) / 256), dim3(256), 0, stream>>>(
      srcIdx, dstIdx, ea, cursor, sSrc, sDst, sEa, E);

  // node encoder: UN (in Sb) -> hS
  k_node_u<<<dim3((N * 32 + 255) / 256), dim3(256), 0, stream>>>(x, ne_w1, ne_b1, ne_a, Sb, N);
  k_enc<<<dim3(gN), dim3(256), 0, stream>>>(Sb, WT, ne_b2, hSh, hSl, N);

  for (int l = 0; l < 5; ++l) {
    const bf16_t* slotL = WT + (size_t)(2 + l * 6) * 32768;
    k_pq<<<dim3(gN, 2), dim3(256), 0, stream>>>(hSh, hSl, slotL, Pb, Qb, N);
    hipMemsetAsync(Sb, 0, NNp * 4, stream);
    k_edge<<<dim3(gE), dim3(256), 0, stream>>>(
        sEa, sSrc, sDst, ee_w1, ee_b1, ee_a,
        slotL + 4 * 32768, bvec + l * 128, le_a + l, Pb, Qb, Sb, E);
    k_svu<<<dim3(gN), dim3(256), 0, stream>>>(
        Sb, hSh, hSl, slotL + 5 * 32768, slotL + 2 * 32768, slotL + 3 * 32768,
        ln_b1 + (size_t)l * 128, btil + l * 128, deg, ln_a + l,
        ln_b2 + (size_t)l * 128, N);
  }

  k_dec<<<dim3(gN), dim3(256), 0, stream>>>(hSh, hSl, WT + 32768, de_b1, de_a,
                                            de_w2, de_b2, out, N);
}